// Round 4
// baseline (177.393 us; speedup 1.0000x reference)
//
#include <hip/hip_runtime.h>
#include <hip/hip_bf16.h>

#define NB 32
#define NT 1024
#define ND 256
#define ETA 0.1f
#define INVS 0.70710678118654752440f

typedef short bf16x8 __attribute__((ext_vector_type(8)));
typedef float f32x4  __attribute__((ext_vector_type(4)));

__device__ inline unsigned short f2bf(float f){
  __hip_bfloat16 h = __float2bfloat16(f);
  return *reinterpret_cast<unsigned short*>(&h);
}
__device__ inline float bf2f(unsigned short u){
  return __uint_as_float(((unsigned int)u) << 16);
}

// ---- in-register Haar primitives (compile-time indices after unroll) ----
template<int N>
__device__ inline void idwt_lvl(float* a, const float* d){
#pragma unroll
  for (int i = N-1; i >= 0; --i){
    float av = a[i], dv = d[i];
    a[2*i]   = (av + dv) * INVS;
    a[2*i+1] = (av - dv) * INVS;
  }
}
template<int N>
__device__ inline void dwt_lvl(float* a, float* d){
#pragma unroll
  for (int i = 0; i < N; ++i){
    float e = a[2*i], o = a[2*i+1];
    a[i] = (e + o) * INVS;
    d[i] = (e - o) * INVS;
  }
}

// stash addressing: chunk-approx a4p[b][j][d] lives in Y rows 16j,16j+1 as fp32
__device__ inline size_t stash_idx(int b, int j, int d){
  return ((size_t)b * NT + 16*j) * 128 + d;
}

// ---------------- K2: S = bf16(IDWT10(w*rho)), no stores of c ----------------
__global__ __launch_bounds__(256) void k_fine_first(const float* __restrict__ rho,
                                                    const float* __restrict__ w,
                                                    unsigned short* __restrict__ S){
  int bx = blockIdx.x;                 // b*64 + j
  int b = bx >> 6, j = bx & 63;
  int d = threadIdx.x;
  size_t cb = ((size_t)b * NT) * ND + d;

  // coarse leaf: 7 coefficients (row0 approx + 1 detail per level)
  float a = rho[cb] * w[d];
#pragma unroll
  for (int l = 6; l >= 1; --l){
    int row = (64 >> l) + (j >> l);
    size_t o = (size_t)row * ND;
    float dv = rho[cb + o] * w[o + d];
    float sgn = ((j >> (l-1)) & 1) ? -1.f : 1.f;
    a = (a + sgn * dv) * INVS;
  }

  // fine coefficients
  float f4, f3[2], f2[4], f1[8];
  { size_t o = (size_t)(64 + j) * ND;  f4 = rho[cb + o] * w[o + d]; }
#pragma unroll
  for (int i = 0; i < 2; ++i){ size_t o = (size_t)(128 + 2*j + i) * ND; f3[i] = rho[cb + o] * w[o + d]; }
#pragma unroll
  for (int i = 0; i < 4; ++i){ size_t o = (size_t)(256 + 4*j + i) * ND; f2[i] = rho[cb + o] * w[o + d]; }
#pragma unroll
  for (int i = 0; i < 8; ++i){ size_t o = (size_t)(512 + 8*j + i) * ND; f1[i] = rho[cb + o] * w[o + d]; }

  float A[16];
  A[0] = a;
  idwt_lvl<1>(A, &f4); idwt_lvl<2>(A, f3); idwt_lvl<4>(A, f2); idwt_lvl<8>(A, f1);
#pragma unroll
  for (int i = 0; i < 16; ++i) S[cb + (size_t)(16*j + i) * ND] = f2bf(A[i]);
}

// ---------------- K4: fine DWT of Y; c' fine rows = blend(w*rho, details); stash chunk approx ----------------
__global__ __launch_bounds__(256) void k_fine_dwt_mid(unsigned short* __restrict__ Y,
                                                      const float* __restrict__ rho,
                                                      const float* __restrict__ w,
                                                      float* __restrict__ c){
  int bx = blockIdx.x;
  int b = bx >> 6, j = bx & 63;
  int d = threadIdx.x;
  size_t cb = ((size_t)b * NT) * ND + d;
  float x[16];
#pragma unroll
  for (int i = 0; i < 16; ++i) x[i] = bf2f(Y[cb + (size_t)(16*j + i) * ND]);
  __syncthreads();                       // all reads of rows 16j..16j+15 done
  float d1[8], d2[4], d3[2], d4;
  dwt_lvl<8>(x, d1); dwt_lvl<4>(x, d2); dwt_lvl<2>(x, d3); dwt_lvl<1>(x, &d4);
  ((float*)Y)[stash_idx(b, j, d)] = x[0];   // chunk approx stash (rows 16j,16j+1)

  { size_t o = (size_t)(64 + j) * ND;
    float cv = rho[cb + o] * w[o + d];  c[cb + o] = cv - ETA*(cv - d4); }
#pragma unroll
  for (int i = 0; i < 2; ++i){ size_t o = (size_t)(128 + 2*j + i) * ND;
    float cv = rho[cb + o] * w[o + d];  c[cb + o] = cv - ETA*(cv - d3[i]); }
#pragma unroll
  for (int i = 0; i < 4; ++i){ size_t o = (size_t)(256 + 4*j + i) * ND;
    float cv = rho[cb + o] * w[o + d];  c[cb + o] = cv - ETA*(cv - d2[i]); }
#pragma unroll
  for (int i = 0; i < 8; ++i){ size_t o = (size_t)(512 + 8*j + i) * ND;
    float cv = rho[cb + o] * w[o + d];  c[cb + o] = cv - ETA*(cv - d1[i]); }
}

// ---------------- K5: coarse path from stash (sibling-segment sums) + fine IDWT -> S ----------------
__global__ __launch_bounds__(256) void k_fine_idwt_mid(const unsigned short* __restrict__ Y,
                                                       const float* __restrict__ rho,
                                                       const float* __restrict__ w,
                                                       float* __restrict__ c,
                                                       unsigned short* __restrict__ S){
  const float* YF = (const float*)Y;
  int bx = blockIdx.x;
  int b = bx >> 6, j = bx & 63;
  int d = threadIdx.x;
  size_t cb = ((size_t)b * NT) * ND + d;

  // j==0 block: full coarse DWT + blend, writes c' rows 0..63 (consumed by k_coarse_final)
  if (j == 0){
    float X[64];
#pragma unroll
    for (int jj = 0; jj < 64; ++jj) X[jj] = YF[stash_idx(b, jj, d)];
    float Yc[64];
    dwt_lvl<32>(X, Yc+32); dwt_lvl<16>(X, Yc+16); dwt_lvl<8>(X, Yc+8);
    dwt_lvl<4>(X, Yc+4);   dwt_lvl<2>(X, Yc+2);   dwt_lvl<1>(X, Yc+1);
    Yc[0] = X[0];
#pragma unroll
    for (int r = 0; r < 64; ++r){
      size_t o = (size_t)r * ND;
      float cv = rho[cb + o] * w[o + d];
      c[cb + o] = cv - ETA*(cv - Yc[r]);
    }
  }

  // path walk: blended coarse coeffs along leaf path, then leaf IDWT
  float ap = YF[stash_idx(b, j, d)];
  float sc = 1.0f;                        // INVS^(l-1)
  float ncl[6];
#pragma unroll
  for (int l = 1; l <= 6; ++l){
    int sibbase = ((j >> (l-1)) ^ 1) << (l-1);
    float ssum = 0.f;
#pragma unroll
    for (int i = 0; i < (1 << (l-1)); ++i)
      ssum += YF[stash_idx(b, sibbase + i, d)];
    float sib = ssum * sc;
    float sgn = ((j >> (l-1)) & 1) ? -1.f : 1.f;
    float detv = sgn * (ap - sib) * INVS;
    ap = (ap + sib) * INVS;
    int row = (64 >> l) + (j >> l);
    size_t o = (size_t)row * ND;
    float cv = rho[cb + o] * w[o + d];
    ncl[l-1] = cv - ETA*(cv - detv);
    sc *= INVS;
  }
  float nc0;
  { float cv = rho[cb] * w[d]; nc0 = cv - ETA*(cv - ap); }

  float a = nc0;
#pragma unroll
  for (int l = 6; l >= 1; --l){
    float sgn = ((j >> (l-1)) & 1) ? -1.f : 1.f;
    a = (a + sgn * ncl[l-1]) * INVS;
  }

  // fine IDWT from c' fine rows (written by k_fine_dwt_mid)
  float f4, f3[2], f2[4], f1[8];
  f4 = c[cb + (size_t)(64 + j) * ND];
#pragma unroll
  for (int i = 0; i < 2; ++i) f3[i] = c[cb + (size_t)(128 + 2*j + i) * ND];
#pragma unroll
  for (int i = 0; i < 4; ++i) f2[i] = c[cb + (size_t)(256 + 4*j + i) * ND];
#pragma unroll
  for (int i = 0; i < 8; ++i) f1[i] = c[cb + (size_t)(512 + 8*j + i) * ND];
  float A[16];
  A[0] = a;
  idwt_lvl<1>(A, &f4); idwt_lvl<2>(A, f3); idwt_lvl<4>(A, f2); idwt_lvl<8>(A, f1);
#pragma unroll
  for (int i = 0; i < 16; ++i) S[cb + (size_t)(16*j + i) * ND] = f2bf(A[i]);
}

// ---------------- K7: fine DWT of Y2; out fine rows = blend(c', details)/w; stash approx ----------------
__global__ __launch_bounds__(256) void k_fine_dwt_final(unsigned short* __restrict__ Y,
                                                        float* __restrict__ c,
                                                        const float* __restrict__ w){
  int bx = blockIdx.x;
  int b = bx >> 6, j = bx & 63;
  int d = threadIdx.x;
  size_t cb = ((size_t)b * NT) * ND + d;
  float x[16];
#pragma unroll
  for (int i = 0; i < 16; ++i) x[i] = bf2f(Y[cb + (size_t)(16*j + i) * ND]);
  __syncthreads();
  float d1[8], d2[4], d3[2], d4;
  dwt_lvl<8>(x, d1); dwt_lvl<4>(x, d2); dwt_lvl<2>(x, d3); dwt_lvl<1>(x, &d4);
  ((float*)Y)[stash_idx(b, j, d)] = x[0];

  { size_t o = (size_t)(64 + j) * ND;
    float cv = c[cb + o];  c[cb + o] = (cv - ETA*(cv - d4)) / w[o + d]; }
#pragma unroll
  for (int i = 0; i < 2; ++i){ size_t o = (size_t)(128 + 2*j + i) * ND;
    float cv = c[cb + o];  c[cb + o] = (cv - ETA*(cv - d3[i])) / w[o + d]; }
#pragma unroll
  for (int i = 0; i < 4; ++i){ size_t o = (size_t)(256 + 4*j + i) * ND;
    float cv = c[cb + o];  c[cb + o] = (cv - ETA*(cv - d2[i])) / w[o + d]; }
#pragma unroll
  for (int i = 0; i < 8; ++i){ size_t o = (size_t)(512 + 8*j + i) * ND;
    float cv = c[cb + o];  c[cb + o] = (cv - ETA*(cv - d1[i])) / w[o + d]; }
}

// ---------------- K8: coarse rows 0..63 of output (tiny) ----------------
__global__ __launch_bounds__(256) void k_coarse_final(const unsigned short* __restrict__ Y,
                                                      float* __restrict__ c,
                                                      const float* __restrict__ w){
  const float* YF = (const float*)Y;
  int g = blockIdx.x * 256 + threadIdx.x;
  int b = g >> 8, d = g & 255;
  float x[64];
#pragma unroll
  for (int jj = 0; jj < 64; ++jj) x[jj] = YF[stash_idx(b, jj, d)];
  float y[64];
  dwt_lvl<32>(x, y+32); dwt_lvl<16>(x, y+16); dwt_lvl<8>(x, y+8);
  dwt_lvl<4>(x, y+4);   dwt_lvl<2>(x, y+2);   dwt_lvl<1>(x, y+1);
  y[0] = x[0];
  size_t cb = ((size_t)b * NT) * ND + d;
#pragma unroll
  for (int r = 0; r < 64; ++r){
    size_t o = (size_t)r * ND;
    float cv = c[cb + o];
    c[cb + o] = (cv - ETA*(cv - y[r])) / w[o + d];
  }
}

// ---------------- per-band GEMM, register-held B panel, TM=2 tiles/block ----------------
__global__ __launch_bounds__(256, 2) void k_band_gemm(const unsigned short* __restrict__ S,
                                                      const unsigned short* __restrict__ Wt,
                                                      const float* __restrict__ bias,
                                                      unsigned short* __restrict__ Y){
  int bx = blockIdx.x;  // 0..591
  int wv = threadIdx.x >> 6, lane = threadIdx.x & 63;
  int row = lane & 15, kg = lane >> 4;
  int band, jbase; bool masked = false;
  if      (bx <  16){ band =  6; jbase = bx*2; }
  else if (bx <  48){ band =  7; jbase = (bx-16)*2; }
  else if (bx < 112){ band =  8; jbase = (bx-48)*2; }
  else if (bx < 240){ band =  9; jbase = (bx-112)*2; }
  else if (bx < 496){ band = 10; jbase = (bx-240)*2; }
  else { masked = true; int mb = bx-496; band = mb>>4; jbase = (mb&15)*2; }

  int n0 = wv * 64;
  const unsigned short* Wb = Wt + (size_t)band * 65536;

  bf16x8 breg[8][4];
#pragma unroll
  for (int kk = 0; kk < 8; ++kk)
#pragma unroll
    for (int ni = 0; ni < 4; ++ni)
      breg[kk][ni] = *(const bf16x8*)(Wb + (size_t)(n0 + 16*ni + row)*256 + kk*32 + kg*8);

  float bv[4];
#pragma unroll
  for (int ni = 0; ni < 4; ++ni) bv[ni] = bias[band*256 + n0 + 16*ni + row];

  int lo = 0, hi = 0;
  if (masked){
    lo = (band == 0) ? 0 : (1 << (band - 1));
    hi = (band == 0) ? 1 : (1 << band);
  }
  int shift = masked ? 0 : (band - 6);
  int tstart = masked ? 0 : (32 << shift);

  for (int m = 0; m < 2; ++m){
    int j = jbase + m;
    int bb, t0;
    if (masked){ bb = j; t0 = 0; }
    else { bb = j >> shift; t0 = tstart + (j & ((1 << shift) - 1)) * 32; }

    f32x4 acc[2][4];
#pragma unroll
    for (int mi = 0; mi < 2; ++mi)
#pragma unroll
      for (int ni = 0; ni < 4; ++ni) acc[mi][ni] = (f32x4){0.f, 0.f, 0.f, 0.f};

    size_t arow0 = ((size_t)bb * NT + t0 + row) * ND;
#pragma unroll
    for (int kk = 0; kk < 8; ++kk){
      int k = kk*32 + kg*8;
      bf16x8 a0 = *(const bf16x8*)(S + arow0 + k);
      bf16x8 a1 = *(const bf16x8*)(S + arow0 + 16*ND + k);
#pragma unroll
      for (int ni = 0; ni < 4; ++ni){
        acc[0][ni] = __builtin_amdgcn_mfma_f32_16x16x32_bf16(a0, breg[kk][ni], acc[0][ni], 0, 0, 0);
        acc[1][ni] = __builtin_amdgcn_mfma_f32_16x16x32_bf16(a1, breg[kk][ni], acc[1][ni], 0, 0, 0);
      }
    }
#pragma unroll
    for (int ni = 0; ni < 4; ++ni){
#pragma unroll
      for (int mi = 0; mi < 2; ++mi){
#pragma unroll
        for (int jj = 0; jj < 4; ++jj){
          int t = t0 + 16*mi + kg*4 + jj;   // C/D: row=(lane>>4)*4+reg, col=lane&15
          if (!masked || (t >= lo && t < hi)){
            Y[((size_t)bb*NT + t)*ND + n0 + 16*ni + row] = f2bf(acc[mi][ni][jj] + bv[ni]);
          }
        }
      }
    }
  }
}

// ---------------- Wt[band][e][d] = bf16(W[band][d][e]) ----------------
__global__ __launch_bounds__(256) void k_wprep(const float* __restrict__ W,
                                               unsigned short* __restrict__ Wt){
  __shared__ float tbuf[32][33];
  int band = blockIdx.y;
  int tile = blockIdx.x;             // 0..63 -> 8x8 grid of 32x32 tiles
  int td0 = (tile >> 3) * 32, te0 = (tile & 7) * 32;
  int tx = threadIdx.x & 31, ty = threadIdx.x >> 5;
#pragma unroll
  for (int i = 0; i < 4; ++i){
    tbuf[ty*4 + i][tx] = W[(size_t)band*65536 + (size_t)(td0 + ty*4 + i)*256 + te0 + tx];
  }
  __syncthreads();
#pragma unroll
  for (int i = 0; i < 4; ++i){
    Wt[(size_t)band*65536 + (size_t)(te0 + ty*4 + i)*256 + td0 + tx] = f2bf(tbuf[tx][ty*4 + i]);
  }
}

extern "C" void kernel_launch(void* const* d_in, const int* in_sizes, int n_in,
                              void* d_out, int out_size, void* d_ws, size_t ws_size,
                              hipStream_t stream){
  const float* rho  = (const float*)d_in[0];
  const float* w    = (const float*)d_in[1];
  const float* W    = (const float*)d_in[2];
  const float* bias = (const float*)d_in[3];

  float* c = (float*)d_out;                                   // blended-state / output buffer
  unsigned short* S  = (unsigned short*)d_ws;                 // 16 MB bf16 signal
  unsigned short* Y  = S + (size_t)NB * NT * ND;              // 16 MB bf16 predicted signal (+ fp32 stash rows)
  unsigned short* Wt = Y + (size_t)NB * NT * ND;              // 1.4 MB bf16 transposed weights

  k_wprep<<<dim3(64, 11), 256, 0, stream>>>(W, Wt);
  k_fine_first<<<NB*64, 256, 0, stream>>>(rho, w, S);
  k_band_gemm<<<592, 256, 0, stream>>>(S, Wt, bias, Y);
  k_fine_dwt_mid<<<NB*64, 256, 0, stream>>>(Y, rho, w, c);
  k_fine_idwt_mid<<<NB*64, 256, 0, stream>>>(Y, rho, w, c, S);
  k_band_gemm<<<592, 256, 0, stream>>>(S, Wt, bias, Y);
  k_fine_dwt_final<<<NB*64, 256, 0, stream>>>(Y, c, w);
  k_coarse_final<<<32, 256, 0, stream>>>(Y, c, w);
}

// Round 5
// 166.713 us; speedup vs baseline: 1.0641x; 1.0641x over previous
//
#include <hip/hip_runtime.h>
#include <hip/hip_bf16.h>

#define NB 32
#define NT 1024
#define ND 256
#define ETA 0.1f
#define INVS 0.70710678118654752440f

#define SP 264   // S-tile LDS pitch (bf16 elems)
#define YP 260   // Y-tile LDS pitch (f32 elems)

typedef short bf16x8 __attribute__((ext_vector_type(8)));
typedef float f32x4  __attribute__((ext_vector_type(4)));

__device__ inline unsigned short f2bf(float f){
  __hip_bfloat16 h = __float2bfloat16(f);
  return *reinterpret_cast<unsigned short*>(&h);
}

template<int N>
__device__ inline void idwt_lvl(float* a, const float* d){
#pragma unroll
  for (int i = N-1; i >= 0; --i){
    float av = a[i], dv = d[i];
    a[2*i]   = (av + dv) * INVS;
    a[2*i+1] = (av - dv) * INVS;
  }
}
template<int N>
__device__ inline void dwt_lvl(float* a, float* d){
#pragma unroll
  for (int i = 0; i < N; ++i){
    float e = a[2*i], o = a[2*i+1];
    a[i] = (e + o) * INVS;
    d[i] = (e - o) * INVS;
  }
}

// ---------------- GEMM phase B helper: one wave computes M32xN32 for given band ----------------
__device__ inline void gemm_tile(const unsigned short* __restrict__ ldsS,
                                 const unsigned short* __restrict__ Wt,
                                 const float* __restrict__ bias,
                                 float* __restrict__ ldsY,
                                 int band, int n0, int row16, int kg,
                                 int lo, int hi){
  const unsigned short* Wb = Wt + (size_t)band * 65536;
  bf16x8 breg[8][2];
#pragma unroll
  for (int kk = 0; kk < 8; ++kk)
#pragma unroll
    for (int ni = 0; ni < 2; ++ni)
      breg[kk][ni] = *(const bf16x8*)(Wb + (size_t)(n0 + 16*ni + row16)*256 + kk*32 + kg*8);
  float bv[2];
#pragma unroll
  for (int ni = 0; ni < 2; ++ni) bv[ni] = bias[band*256 + n0 + 16*ni + row16];

  f32x4 acc[2][2];
#pragma unroll
  for (int mi = 0; mi < 2; ++mi)
#pragma unroll
    for (int ni = 0; ni < 2; ++ni) acc[mi][ni] = (f32x4){0.f,0.f,0.f,0.f};

#pragma unroll
  for (int kk = 0; kk < 8; ++kk){
    bf16x8 a0 = *(const bf16x8*)&ldsS[row16*SP + kk*32 + kg*8];
    bf16x8 a1 = *(const bf16x8*)&ldsS[(16+row16)*SP + kk*32 + kg*8];
#pragma unroll
    for (int ni = 0; ni < 2; ++ni){
      acc[0][ni] = __builtin_amdgcn_mfma_f32_16x16x32_bf16(a0, breg[kk][ni], acc[0][ni], 0,0,0);
      acc[1][ni] = __builtin_amdgcn_mfma_f32_16x16x32_bf16(a1, breg[kk][ni], acc[1][ni], 0,0,0);
    }
  }
#pragma unroll
  for (int mi = 0; mi < 2; ++mi)
#pragma unroll
    for (int ni = 0; ni < 2; ++ni)
#pragma unroll
      for (int r = 0; r < 4; ++r){
        int trow = 16*mi + kg*4 + r;
        if (trow >= lo && trow < hi)
          ldsY[trow*YP + n0 + 16*ni + row16] = acc[mi][ni][r] + bv[ni];
      }
}

// ---------------- K2: step1 fused  (fine-IDWT -> GEMM -> fine-DWT+blend -> c', stash1) ----------------
__global__ __launch_bounds__(512,4) void k_step1(const float* __restrict__ rho,
                                                 const float* __restrict__ w,
                                                 const unsigned short* __restrict__ Wt,
                                                 const float* __restrict__ bias,
                                                 float* __restrict__ c,
                                                 float* __restrict__ stash1){
  __shared__ unsigned short ldsS[32*SP];
  __shared__ float ldsY[32*YP];
  int bx = blockIdx.x;
  int b = bx & 31, p = bx >> 5;          // p=0 (mixed) blocks launch first
  int tid = threadIdx.x;
  int jj = tid >> 8, d = tid & 255;
  int j = 2*p + jj;
  size_t cb = ((size_t)b*NT)*ND + d;

  // ---- phase A: coarse leaf (7 coeffs) + fine coeffs -> 16-row IDWT -> LDS
  float a0 = rho[cb] * w[d];
#pragma unroll
  for (int l = 6; l >= 1; --l){
    int row = (64>>l) + (j>>l); size_t o = (size_t)row*ND;
    float dv = rho[cb+o] * w[o+d];
    float sgn = ((j>>(l-1))&1) ? -1.f : 1.f;
    a0 = (a0 + sgn*dv) * INVS;
  }
  float f4, f3[2], f2[4], f1[8];
  { size_t o = (size_t)(64+j)*ND;  f4 = rho[cb+o]*w[o+d]; }
#pragma unroll
  for (int i = 0; i < 2; ++i){ size_t o = (size_t)(128+2*j+i)*ND; f3[i] = rho[cb+o]*w[o+d]; }
#pragma unroll
  for (int i = 0; i < 4; ++i){ size_t o = (size_t)(256+4*j+i)*ND; f2[i] = rho[cb+o]*w[o+d]; }
#pragma unroll
  for (int i = 0; i < 8; ++i){ size_t o = (size_t)(512+8*j+i)*ND; f1[i] = rho[cb+o]*w[o+d]; }
  {
    float A[16]; A[0] = a0;
    idwt_lvl<1>(A,&f4); idwt_lvl<2>(A,f3); idwt_lvl<4>(A,f2); idwt_lvl<8>(A,f1);
#pragma unroll
    for (int i = 0; i < 16; ++i) ldsS[(16*jj+i)*SP + d] = f2bf(A[i]);
  }
  __syncthreads();

  // ---- phase B: GEMM rows 32p..32p+31
  {
    int wv = tid>>6, lane = tid&63, row16 = lane&15, kg = lane>>4;
    int n0 = wv*32;
    if (p > 0){
      int band = 32 - __clz(32*p);
      gemm_tile(ldsS, Wt, bias, ldsY, band, n0, row16, kg, 0, 32);
    } else {
#pragma unroll
      for (int bd = 0; bd < 6; ++bd){
        int lo = (bd==0) ? 0 : (1<<(bd-1));
        int hi = (bd==0) ? 1 : (1<<bd);
        gemm_tile(ldsS, Wt, bias, ldsY, bd, n0, row16, kg, lo, hi);
      }
    }
  }
  __syncthreads();

  // ---- phase C: fine DWT of Y-tile; blend with cached coeffs; store c' + stash
  float x[16];
#pragma unroll
  for (int i = 0; i < 16; ++i) x[i] = ldsY[(16*jj+i)*YP + d];
  float d1[8], d2[4], d3[2], d4v;
  dwt_lvl<8>(x,d1); dwt_lvl<4>(x,d2); dwt_lvl<2>(x,d3); dwt_lvl<1>(x,&d4v);
  stash1[((size_t)b*256 + d)*64 + j] = x[0];
  { size_t o = (size_t)(64+j)*ND;  c[cb+o] = f4 - ETA*(f4 - d4v); }
#pragma unroll
  for (int i = 0; i < 2; ++i){ size_t o = (size_t)(128+2*j+i)*ND; c[cb+o] = f3[i] - ETA*(f3[i] - d3[i]); }
#pragma unroll
  for (int i = 0; i < 4; ++i){ size_t o = (size_t)(256+4*j+i)*ND; c[cb+o] = f2[i] - ETA*(f2[i] - d2[i]); }
#pragma unroll
  for (int i = 0; i < 8; ++i){ size_t o = (size_t)(512+8*j+i)*ND; c[cb+o] = f1[i] - ETA*(f1[i] - d1[i]); }
}

// ---------------- K3: step2 fused  (coarse tree from stash1 + c' IDWT -> GEMM -> final DWT/blend/div) ----------------
__global__ __launch_bounds__(512,4) void k_step2(const float* __restrict__ rho,
                                                 const float* __restrict__ w,
                                                 const unsigned short* __restrict__ Wt,
                                                 const float* __restrict__ bias,
                                                 float* __restrict__ c,
                                                 const float* __restrict__ stash1,
                                                 float* __restrict__ stash2){
  __shared__ unsigned short ldsS[32*SP];
  __shared__ float ldsY[32*YP];
  int bx = blockIdx.x;
  int b = bx & 31, p = bx >> 5;
  int tid = threadIdx.x;
  int jj = tid >> 8, d = tid & 255;
  int j = 2*p + jj;
  size_t cb = ((size_t)b*NT)*ND + d;

  // ---- phase A: register coarse tree from transposed stash + path blend -> leaf
  const float* sp = stash1 + ((size_t)b*256 + d)*64;
  float qs[16];
#pragma unroll
  for (int q = 0; q < 16; ++q){
    float4 v = *(const float4*)(sp + 4*q);
    qs[q] = (v.x + v.y) + (v.z + v.w);
  }
  float4 ov = *(const float4*)(sp + 4*(j>>2));
  float ownq[4] = {ov.x, ov.y, ov.z, ov.w};

  float sib[6];
  sib[0] = ownq[(j^1)&3];
  { int s2 = (((j>>1)^1)<<1)&3; sib[1] = (ownq[s2] + ownq[s2+1]) * INVS; }
  sib[2] = qs[(j>>2)^1] * 0.5f;
  { int q4 = ((j>>3)^1)<<1; sib[3] = (qs[q4] + qs[q4+1]) * (0.5f*INVS); }
  { int q5 = ((j>>4)^1)<<2; sib[4] = ((qs[q5]+qs[q5+1])+(qs[q5+2]+qs[q5+3])) * 0.25f; }
  { int q6 = ((j>>5)^1)<<3;
    sib[5] = (((qs[q6]+qs[q6+1])+(qs[q6+2]+qs[q6+3]))+((qs[q6+4]+qs[q6+5])+(qs[q6+6]+qs[q6+7]))) * (0.25f*INVS); }

  float ap = ownq[j&3];
  float ncl[6];
#pragma unroll
  for (int l = 1; l <= 6; ++l){
    float sgn = ((j>>(l-1))&1) ? -1.f : 1.f;
    float detv = sgn * (ap - sib[l-1]) * INVS;
    ap = (ap + sib[l-1]) * INVS;
    int row = (64>>l) + (j>>l); size_t o = (size_t)row*ND;
    float cv = rho[cb+o] * w[o+d];
    ncl[l-1] = cv - ETA*(cv - detv);
  }
  float a0;
  { float cv = rho[cb] * w[d]; a0 = cv - ETA*(cv - ap); }
#pragma unroll
  for (int l = 6; l >= 1; --l){
    float sgn = ((j>>(l-1))&1) ? -1.f : 1.f;
    a0 = (a0 + sgn*ncl[l-1]) * INVS;
  }

  // fine coeffs from c' (cache for phase C)
  float f4, f3[2], f2[4], f1[8];
  f4 = c[cb + (size_t)(64+j)*ND];
#pragma unroll
  for (int i = 0; i < 2; ++i) f3[i] = c[cb + (size_t)(128+2*j+i)*ND];
#pragma unroll
  for (int i = 0; i < 4; ++i) f2[i] = c[cb + (size_t)(256+4*j+i)*ND];
#pragma unroll
  for (int i = 0; i < 8; ++i) f1[i] = c[cb + (size_t)(512+8*j+i)*ND];
  {
    float A[16]; A[0] = a0;
    idwt_lvl<1>(A,&f4); idwt_lvl<2>(A,f3); idwt_lvl<4>(A,f2); idwt_lvl<8>(A,f1);
#pragma unroll
    for (int i = 0; i < 16; ++i) ldsS[(16*jj+i)*SP + d] = f2bf(A[i]);
  }
  __syncthreads();

  // ---- phase B
  {
    int wv = tid>>6, lane = tid&63, row16 = lane&15, kg = lane>>4;
    int n0 = wv*32;
    if (p > 0){
      int band = 32 - __clz(32*p);
      gemm_tile(ldsS, Wt, bias, ldsY, band, n0, row16, kg, 0, 32);
    } else {
#pragma unroll
      for (int bd = 0; bd < 6; ++bd){
        int lo = (bd==0) ? 0 : (1<<(bd-1));
        int hi = (bd==0) ? 1 : (1<<bd);
        gemm_tile(ldsS, Wt, bias, ldsY, bd, n0, row16, kg, lo, hi);
      }
    }
  }
  __syncthreads();

  // ---- phase C: final DWT, blend, divide by w, store out + stash2
  float x[16];
#pragma unroll
  for (int i = 0; i < 16; ++i) x[i] = ldsY[(16*jj+i)*YP + d];
  float d1[8], d2[4], d3[2], d4v;
  dwt_lvl<8>(x,d1); dwt_lvl<4>(x,d2); dwt_lvl<2>(x,d3); dwt_lvl<1>(x,&d4v);
  stash2[((size_t)b*256 + d)*64 + j] = x[0];
  { size_t o = (size_t)(64+j)*ND;  c[cb+o] = (f4 - ETA*(f4 - d4v)) / w[o+d]; }
#pragma unroll
  for (int i = 0; i < 2; ++i){ size_t o = (size_t)(128+2*j+i)*ND; c[cb+o] = (f3[i] - ETA*(f3[i] - d3[i])) / w[o+d]; }
#pragma unroll
  for (int i = 0; i < 4; ++i){ size_t o = (size_t)(256+4*j+i)*ND; c[cb+o] = (f2[i] - ETA*(f2[i] - d2[i])) / w[o+d]; }
#pragma unroll
  for (int i = 0; i < 8; ++i){ size_t o = (size_t)(512+8*j+i)*ND; c[cb+o] = (f1[i] - ETA*(f1[i] - d1[i])) / w[o+d]; }
}

// ---------------- K4: coarse rows 0..63 of output ----------------
__global__ __launch_bounds__(256) void k_final(const float* __restrict__ rho,
                                               const float* __restrict__ w,
                                               const float* __restrict__ stash1,
                                               const float* __restrict__ stash2,
                                               float* __restrict__ c){
  int g = blockIdx.x*256 + threadIdx.x;
  int b = g >> 8, d = g & 255;
  size_t cb = ((size_t)b*NT)*ND + d;
  const float* s1 = stash1 + ((size_t)b*256 + d)*64;
  float x[64];
#pragma unroll
  for (int q = 0; q < 16; ++q){
    float4 v = *(const float4*)(s1 + 4*q);
    x[4*q] = v.x; x[4*q+1] = v.y; x[4*q+2] = v.z; x[4*q+3] = v.w;
  }
  float y[64];
  dwt_lvl<32>(x,y+32); dwt_lvl<16>(x,y+16); dwt_lvl<8>(x,y+8);
  dwt_lvl<4>(x,y+4);   dwt_lvl<2>(x,y+2);   dwt_lvl<1>(x,y+1);
  y[0] = x[0];
  float cr[64];
#pragma unroll
  for (int r = 0; r < 64; ++r){
    size_t o = (size_t)r*ND;
    float cv = rho[cb+o]*w[o+d];
    cr[r] = cv - ETA*(cv - y[r]);
  }
  const float* s2 = stash2 + ((size_t)b*256 + d)*64;
  float x2[64];
#pragma unroll
  for (int q = 0; q < 16; ++q){
    float4 v = *(const float4*)(s2 + 4*q);
    x2[4*q] = v.x; x2[4*q+1] = v.y; x2[4*q+2] = v.z; x2[4*q+3] = v.w;
  }
  float y2[64];
  dwt_lvl<32>(x2,y2+32); dwt_lvl<16>(x2,y2+16); dwt_lvl<8>(x2,y2+8);
  dwt_lvl<4>(x2,y2+4);   dwt_lvl<2>(x2,y2+2);   dwt_lvl<1>(x2,y2+1);
  y2[0] = x2[0];
#pragma unroll
  for (int r = 0; r < 64; ++r){
    size_t o = (size_t)r*ND;
    c[cb+o] = (cr[r] - ETA*(cr[r] - y2[r])) / w[o+d];
  }
}

// ---------------- Wt[band][e][d] = bf16(W[band][d][e]) ----------------
__global__ __launch_bounds__(256) void k_wprep(const float* __restrict__ W,
                                               unsigned short* __restrict__ Wt){
  __shared__ float tbuf[32][33];
  int band = blockIdx.y;
  int tile = blockIdx.x;
  int td0 = (tile >> 3) * 32, te0 = (tile & 7) * 32;
  int tx = threadIdx.x & 31, ty = threadIdx.x >> 5;
#pragma unroll
  for (int i = 0; i < 4; ++i)
    tbuf[ty*4 + i][tx] = W[(size_t)band*65536 + (size_t)(td0 + ty*4 + i)*256 + te0 + tx];
  __syncthreads();
#pragma unroll
  for (int i = 0; i < 4; ++i)
    Wt[(size_t)band*65536 + (size_t)(te0 + ty*4 + i)*256 + td0 + tx] = f2bf(tbuf[tx][ty*4 + i]);
}

extern "C" void kernel_launch(void* const* d_in, const int* in_sizes, int n_in,
                              void* d_out, int out_size, void* d_ws, size_t ws_size,
                              hipStream_t stream){
  const float* rho  = (const float*)d_in[0];
  const float* w    = (const float*)d_in[1];
  const float* W    = (const float*)d_in[2];
  const float* bias = (const float*)d_in[3];

  float* c = (float*)d_out;
  unsigned short* Wt = (unsigned short*)d_ws;                 // 1.44 MB
  float* stash1 = (float*)(Wt + (size_t)11*65536);            // 2 MB  [b][d][64]
  float* stash2 = stash1 + (size_t)NB*256*64;                 // 2 MB  [b][d][64]

  k_wprep<<<dim3(64, 11), 256, 0, stream>>>(W, Wt);
  k_step1<<<NB*32, 512, 0, stream>>>(rho, w, Wt, bias, c, stash1);
  k_step2<<<NB*32, 512, 0, stream>>>(rho, w, Wt, bias, c, stash1, stash2);
  k_final<<<32, 256, 0, stream>>>(rho, w, stash1, stash2, c);
}